// Round 1
// baseline (304.952 us; speedup 1.0000x reference)
//
#include <hip/hip_runtime.h>

#define N_UNITS 8192
#define N_STEPS 256
#define TSLICE 32  // time-steps written per wave

// f32 rounding of exp(-0.001/0.01) = exp(-0.1); matches numpy's cast of the
// python float scalar (NEP50 weak-scalar promotion keeps f32 compute).
__device__ const float ALPHA = 0.90483741803595957066f;

// ---------------------------------------------------------------------------
// LIF recurrence with time-slice replication.
//
//   W == eye => input current == x[i] (bit-exact; see previous notes).
//   V' = (ALPHA*V + I) * (1 - Z);  Z' = (V' > 1)
//
// The recurrence over t is serial, but the dependent ALU chain is ~3 VALU
// ops/step (~1.7 us for all 256 steps) — negligible. The old kernel's cost
// was store latency with 128 single-wave workgroups (1 wave/CU, half the
// CUs idle, per-iteration vmcnt wait on the Z register reuse). Here each
// wave redundantly recomputes the recurrence from t=0 with the EXACT same
// op sequence (bit-identical spikes) and stores only its own 32-step slice:
//   grid = (8192/64 unit-groups) x (2 slice-groups), block = 256 (4 waves)
//   wave w of block (bx,by) -> units bx*64+lane, slice by*4+w (32 steps)
// => 1024 waves = 4 waves/CU on all 256 CUs; 32 coalesced stores per wave.
//
// __fmul_rn/__fadd_rn block FMA contraction so rounding matches numpy
// exactly (spike decisions sit on an exact float compare; one flip =
// absmax 1.0). (V - 1 > 0) <=> (V > 1) exactly in f32.
// ---------------------------------------------------------------------------
__global__ __launch_bounds__(256) void lif_kernel(
    const float* __restrict__ x, float* __restrict__ out) {
  const int lane = threadIdx.x & 63;
  const int wave = threadIdx.x >> 6;
  const int unit = blockIdx.x * 64 + lane;
  const int slice = blockIdx.y * 4 + wave;
  const int t0 = slice * TSLICE;

  const float I = x[unit];

  float V = 0.f;
  float Z = 0.f;

  // Warm-up: steps before this wave's slice — compute only, identical op
  // order to the reference recurrence (bit-exact replication).
  for (int t = 0; t < t0; ++t) {
    const float decayed = __fmul_rn(ALPHA, V);
    const float integ = __fadd_rn(decayed, I);
    V = __fmul_rn(integ, 1.0f - Z);
    Z = (V > 1.0f) ? 1.0f : 0.0f;
  }

  // Owned slice: compute + store 32 rows, coalesced 256B per wave per row.
  float* o = out + (size_t)t0 * N_UNITS + unit;
#pragma unroll
  for (int t = 0; t < TSLICE; ++t) {
    const float decayed = __fmul_rn(ALPHA, V);
    const float integ = __fadd_rn(decayed, I);
    V = __fmul_rn(integ, 1.0f - Z);
    Z = (V > 1.0f) ? 1.0f : 0.0f;
    *o = Z;
    o += N_UNITS;
  }
}

extern "C" void kernel_launch(void* const* d_in, const int* in_sizes, int n_in,
                              void* d_out, int out_size, void* d_ws,
                              size_t ws_size, hipStream_t stream) {
  const float* x = (const float*)d_in[0];
  float* out = (float*)d_out;

  dim3 grid(N_UNITS / 64, N_STEPS / (TSLICE * 4));
  lif_kernel<<<grid, 256, 0, stream>>>(x, out);
}